// Round 1
// baseline (224.375 us; speedup 1.0000x reference)
//
#include <hip/hip_runtime.h>

#define IO_DIM 64
#define WIDTH 16
#define HID 128
#define BS_ (IO_DIM * WIDTH)     // 1024
#define OUT_ (2 * BS_ + WIDTH)   // 2064
#define RPT 4                    // rows per thread in main kernel

// ws layout (floats): u[0..1024), w[1024..2048), bb[2048..2064), uw[2064..2080)

__device__ __forceinline__ float fast_tanh(float x) {
    // tanh(x) = 1 - 2/(1+exp(2x)); __expf -> v_exp_f32, ~1 ulp
    float e = __expf(2.0f * x);
    return 1.0f - __fdividef(2.0f, e + 1.0f);
}

__global__ __launch_bounds__(128) void cnf_prep(
    const float* __restrict__ t, const float* __restrict__ W1,
    const float* __restrict__ b1, const float* __restrict__ W2,
    const float* __restrict__ b2, const float* __restrict__ W3,
    const float* __restrict__ b3, float* __restrict__ ws)
{
    __shared__ float h1[HID];
    __shared__ float h2[HID];
    __shared__ float su[64], sw[64];
    const int tid = threadIdx.x;

    // layer 1: h1 = tanh(W1*t + b1)
    h1[tid] = tanhf(W1[tid] * t[0] + b1[tid]);
    __syncthreads();

    // layer 2: h2 = tanh(W2 @ h1 + b2)
    {
        float s = b2[tid];
        const float4* W2v = (const float4*)(W2 + tid * HID);
        #pragma unroll 8
        for (int k = 0; k < HID / 4; ++k) {
            float4 wv = W2v[k];
            s = fmaf(wv.x, h1[4 * k + 0], s);
            s = fmaf(wv.y, h1[4 * k + 1], s);
            s = fmaf(wv.z, h1[4 * k + 2], s);
            s = fmaf(wv.w, h1[4 * k + 3], s);
        }
        h2[tid] = tanhf(s);
    }
    __syncthreads();

    const int b = blockIdx.x;
    if (b < 16) {
        // blocks 0..15: 64 rows of u (threads 0..63) and 64 rows of w (threads 64..127)
        const int half = tid >> 6;   // 0 -> u, 1 -> w
        const int i = tid & 63;
        const int row = half * BS_ + b * 64 + i;
        float s = b3[row];
        const float4* W3v = (const float4*)(W3 + row * HID);
        #pragma unroll 8
        for (int k = 0; k < HID / 4; ++k) {
            float4 wv = W3v[k];
            s = fmaf(wv.x, h2[4 * k + 0], s);
            s = fmaf(wv.y, h2[4 * k + 1], s);
            s = fmaf(wv.z, h2[4 * k + 2], s);
            s = fmaf(wv.w, h2[4 * k + 3], s);
        }
        ws[half * BS_ + b * 64 + i] = s;
        if (half == 0) su[i] = s; else sw[i] = s;
        __syncthreads();
        if (tid < 64) {
            float p = su[tid] * sw[tid];
            #pragma unroll
            for (int m = 32; m >= 1; m >>= 1) p += __shfl_xor(p, m, 64);
            if (tid == 0) ws[2 * BS_ + WIDTH + b] = p;   // uw[b]
        }
    } else {
        // block 16: bb (16 rows)
        if (tid < WIDTH) {
            const int row = 2 * BS_ + tid;
            float s = b3[row];
            const float4* W3v = (const float4*)(W3 + row * HID);
            #pragma unroll 8
            for (int k = 0; k < HID / 4; ++k) {
                float4 wv = W3v[k];
                s = fmaf(wv.x, h2[4 * k + 0], s);
                s = fmaf(wv.y, h2[4 * k + 1], s);
                s = fmaf(wv.z, h2[4 * k + 2], s);
                s = fmaf(wv.w, h2[4 * k + 3], s);
            }
            ws[2 * BS_ + tid] = s;   // bb[tid]
        }
    }
}

__global__ __launch_bounds__(256) void cnf_main(
    const float* __restrict__ z, const float* __restrict__ ws,
    float* __restrict__ dz, float* __restrict__ dlog, int n)
{
    __shared__ __align__(16) float su[BS_];
    __shared__ __align__(16) float sw[BS_];
    __shared__ float sbb[WIDTH];
    __shared__ float suw[WIDTH];
    const int tid = threadIdx.x;

    for (int idx = tid; idx < BS_; idx += 256) {
        su[idx] = ws[idx] * (1.0f / WIDTH);   // fold dz scale into u
        sw[idx] = ws[BS_ + idx];
    }
    if (tid < WIDTH) {
        sbb[tid] = ws[2 * BS_ + tid];
        suw[tid] = ws[2 * BS_ + WIDTH + tid] * (-1.0f / WIDTH); // fold -1/W into uw
    }
    __syncthreads();

    const float4* zv = (const float4*)z;
    float4* dzv = (float4*)dz;
    const float4* su4 = (const float4*)su;
    const float4* sw4 = (const float4*)sw;

    int rows[RPT];
    bool val[RPT];
    const int base = blockIdx.x * (256 * RPT) + tid;
    #pragma unroll
    for (int p = 0; p < RPT; ++p) { rows[p] = base + p * 256; val[p] = rows[p] < n; }

    // phase 1: a = z @ w^T + bb
    float a[RPT][WIDTH];
    #pragma unroll
    for (int j = 0; j < WIDTH; ++j) {
        float bbv = sbb[j];
        #pragma unroll
        for (int p = 0; p < RPT; ++p) a[p][j] = bbv;
    }

    float4 z4c[RPT];
    #pragma unroll
    for (int p = 0; p < RPT; ++p)
        z4c[p] = val[p] ? zv[rows[p] * 16] : make_float4(0, 0, 0, 0);

    for (int k4 = 0; k4 < 16; ++k4) {
        float4 z4[RPT];
        #pragma unroll
        for (int p = 0; p < RPT; ++p) z4[p] = z4c[p];
        if (k4 < 15) {
            #pragma unroll
            for (int p = 0; p < RPT; ++p)
                z4c[p] = val[p] ? zv[rows[p] * 16 + k4 + 1] : make_float4(0, 0, 0, 0);
        }
        #pragma unroll
        for (int j = 0; j < WIDTH; ++j) {
            float4 w4 = sw4[j * 16 + k4];
            #pragma unroll
            for (int p = 0; p < RPT; ++p) {
                a[p][j] = fmaf(z4[p].x, w4.x, a[p][j]);
                a[p][j] = fmaf(z4[p].y, w4.y, a[p][j]);
                a[p][j] = fmaf(z4[p].z, w4.z, a[p][j]);
                a[p][j] = fmaf(z4[p].w, w4.w, a[p][j]);
            }
        }
    }

    // tanh + trace (dlogp = sum_j (1-th^2) * (-uw_j/16))
    float tr[RPT];
    #pragma unroll
    for (int p = 0; p < RPT; ++p) tr[p] = 0.0f;
    #pragma unroll
    for (int j = 0; j < WIDTH; ++j) {
        float uwj = suw[j];
        #pragma unroll
        for (int p = 0; p < RPT; ++p) {
            float th = fast_tanh(a[p][j]);
            a[p][j] = th;
            tr[p] = fmaf(1.0f - th * th, uwj, tr[p]);
        }
    }
    #pragma unroll
    for (int p = 0; p < RPT; ++p)
        if (val[p]) dlog[rows[p]] = tr[p];

    // phase 2: dz = th @ (u/16)
    for (int k4 = 0; k4 < 16; ++k4) {
        float4 o[RPT];
        #pragma unroll
        for (int p = 0; p < RPT; ++p) o[p] = make_float4(0, 0, 0, 0);
        #pragma unroll
        for (int j = 0; j < WIDTH; ++j) {
            float4 u4 = su4[j * 16 + k4];
            #pragma unroll
            for (int p = 0; p < RPT; ++p) {
                o[p].x = fmaf(a[p][j], u4.x, o[p].x);
                o[p].y = fmaf(a[p][j], u4.y, o[p].y);
                o[p].z = fmaf(a[p][j], u4.z, o[p].z);
                o[p].w = fmaf(a[p][j], u4.w, o[p].w);
            }
        }
        #pragma unroll
        for (int p = 0; p < RPT; ++p)
            if (val[p]) dzv[rows[p] * 16 + k4] = o[p];
    }
}

extern "C" void kernel_launch(void* const* d_in, const int* in_sizes, int n_in,
                              void* d_out, int out_size, void* d_ws, size_t ws_size,
                              hipStream_t stream) {
    const float* t  = (const float*)d_in[0];
    const float* z  = (const float*)d_in[1];
    const float* W1 = (const float*)d_in[2];
    const float* b1 = (const float*)d_in[3];
    const float* W2 = (const float*)d_in[4];
    const float* b2 = (const float*)d_in[5];
    const float* W3 = (const float*)d_in[6];
    const float* b3 = (const float*)d_in[7];

    const int n = in_sizes[1] / IO_DIM;   // 500000
    float* ws   = (float*)d_ws;
    float* out  = (float*)d_out;
    float* dz   = out;
    float* dlog = out + (size_t)n * IO_DIM;

    cnf_prep<<<17, 128, 0, stream>>>(t, W1, b1, W2, b2, W3, b3, ws);

    const int rows_per_block = 256 * RPT;
    const int grid = (n + rows_per_block - 1) / rows_per_block;
    cnf_main<<<grid, 256, 0, stream>>>(z, ws, dz, dlog, n);
}

// Round 2
// 94.443 us; speedup vs baseline: 2.3758x; 2.3758x over previous
//
#include <hip/hip_runtime.h>

#define IO_DIM 64
#define WIDTH 16
#define HID 128
#define BS_ (IO_DIM * WIDTH)     // 1024
#define OUT_ (2 * BS_ + WIDTH)   // 2064
#define TILE_ROWS 256
#define LDW 17                   // float4 stride per tile row (68 floats, bank-balanced)

// ws layout (floats): u[0..1024), w[1024..2048), bb[2048..2064), uw[2064..2080)

__device__ __forceinline__ float fast_tanh(float x) {
    float e = __expf(2.0f * x);
    return 1.0f - __fdividef(2.0f, e + 1.0f);
}

__global__ __launch_bounds__(128) void cnf_prep(
    const float* __restrict__ t, const float* __restrict__ W1,
    const float* __restrict__ b1, const float* __restrict__ W2,
    const float* __restrict__ b2, const float* __restrict__ W3,
    const float* __restrict__ b3, float* __restrict__ ws)
{
    __shared__ float h1[HID];
    __shared__ float h2[HID];
    __shared__ float su[64], sw[64];
    const int tid = threadIdx.x;

    h1[tid] = tanhf(W1[tid] * t[0] + b1[tid]);
    __syncthreads();

    {
        float s = b2[tid];
        const float4* W2v = (const float4*)(W2 + tid * HID);
        #pragma unroll 8
        for (int k = 0; k < HID / 4; ++k) {
            float4 wv = W2v[k];
            s = fmaf(wv.x, h1[4 * k + 0], s);
            s = fmaf(wv.y, h1[4 * k + 1], s);
            s = fmaf(wv.z, h1[4 * k + 2], s);
            s = fmaf(wv.w, h1[4 * k + 3], s);
        }
        h2[tid] = tanhf(s);
    }
    __syncthreads();

    const int b = blockIdx.x;
    if (b < 16) {
        const int half = tid >> 6;   // 0 -> u, 1 -> w
        const int i = tid & 63;
        const int row = half * BS_ + b * 64 + i;
        float s = b3[row];
        const float4* W3v = (const float4*)(W3 + row * HID);
        #pragma unroll 8
        for (int k = 0; k < HID / 4; ++k) {
            float4 wv = W3v[k];
            s = fmaf(wv.x, h2[4 * k + 0], s);
            s = fmaf(wv.y, h2[4 * k + 1], s);
            s = fmaf(wv.z, h2[4 * k + 2], s);
            s = fmaf(wv.w, h2[4 * k + 3], s);
        }
        ws[half * BS_ + b * 64 + i] = s;
        if (half == 0) su[i] = s; else sw[i] = s;
        __syncthreads();
        if (tid < 64) {
            float p = su[tid] * sw[tid];
            #pragma unroll
            for (int m = 32; m >= 1; m >>= 1) p += __shfl_xor(p, m, 64);
            if (tid == 0) ws[2 * BS_ + WIDTH + b] = p;   // uw[b]
        }
    } else {
        if (tid < WIDTH) {
            const int row = 2 * BS_ + tid;
            float s = b3[row];
            const float4* W3v = (const float4*)(W3 + row * HID);
            #pragma unroll 8
            for (int k = 0; k < HID / 4; ++k) {
                float4 wv = W3v[k];
                s = fmaf(wv.x, h2[4 * k + 0], s);
                s = fmaf(wv.y, h2[4 * k + 1], s);
                s = fmaf(wv.z, h2[4 * k + 2], s);
                s = fmaf(wv.w, h2[4 * k + 3], s);
            }
            ws[2 * BS_ + tid] = s;   // bb[tid]
        }
    }
}

__global__ __launch_bounds__(256) void cnf_main(
    const float* __restrict__ z, const float* __restrict__ ws,
    float* __restrict__ dz, float* __restrict__ dlog, int n)
{
    __shared__ __align__(16) float4 tile[TILE_ROWS * LDW];   // 69632 B, z then dz
    __shared__ __align__(16) float su[BS_];
    __shared__ __align__(16) float sw[BS_];
    __shared__ float sbb[WIDTH];
    __shared__ float suw[WIDTH];
    const int tid = threadIdx.x;

    for (int idx = tid; idx < BS_; idx += 256) {
        su[idx] = ws[idx] * (1.0f / WIDTH);   // fold dz scale into u
        sw[idx] = ws[BS_ + idx];
    }
    if (tid < WIDTH) {
        sbb[tid] = ws[2 * BS_ + tid];
        suw[tid] = ws[2 * BS_ + WIDTH + tid] * (-1.0f / WIDTH);
    }

    const int base_row = blockIdx.x * TILE_ROWS;
    const int nrows = min(TILE_ROWS, n - base_row);
    const int nvec = nrows * 16;

    // cooperative z load: contiguous 4 KB per wave-instruction
    const float4* zg = (const float4*)z + (size_t)base_row * 16;
    for (int idx = tid; idx < nvec; idx += 256) {
        int r = idx >> 4, c = idx & 15;
        tile[r * LDW + c] = zg[idx];
    }
    __syncthreads();

    const float4* su4 = (const float4*)su;
    const float4* sw4 = (const float4*)sw;

    if (tid < nrows) {
        // phase 1: a = z @ w^T + bb
        float a[WIDTH];
        #pragma unroll
        for (int j = 0; j < WIDTH; ++j) a[j] = sbb[j];

        #pragma unroll
        for (int k4 = 0; k4 < 16; ++k4) {
            float4 z4 = tile[tid * LDW + k4];
            #pragma unroll
            for (int j = 0; j < WIDTH; ++j) {
                float4 w4 = sw4[j * 16 + k4];
                a[j] = fmaf(z4.x, w4.x, a[j]);
                a[j] = fmaf(z4.y, w4.y, a[j]);
                a[j] = fmaf(z4.z, w4.z, a[j]);
                a[j] = fmaf(z4.w, w4.w, a[j]);
            }
        }

        // tanh + trace
        float tr = 0.0f;
        #pragma unroll
        for (int j = 0; j < WIDTH; ++j) {
            float th = fast_tanh(a[j]);
            a[j] = th;
            tr = fmaf(1.0f - th * th, suw[j], tr);
        }
        dlog[base_row + tid] = tr;

        // phase 2: dz = th @ (u/16), write into own tile row (no barrier needed:
        // each thread reads/writes only row `tid` of the tile)
        #pragma unroll
        for (int k4 = 0; k4 < 16; ++k4) {
            float4 o = make_float4(0.f, 0.f, 0.f, 0.f);
            #pragma unroll
            for (int j = 0; j < WIDTH; ++j) {
                float4 u4 = su4[j * 16 + k4];
                o.x = fmaf(a[j], u4.x, o.x);
                o.y = fmaf(a[j], u4.y, o.y);
                o.z = fmaf(a[j], u4.z, o.z);
                o.w = fmaf(a[j], u4.w, o.w);
            }
            tile[tid * LDW + k4] = o;
        }
    }
    __syncthreads();

    // cooperative dz store: contiguous 4 KB per wave-instruction
    float4* dzg = (float4*)dz + (size_t)base_row * 16;
    for (int idx = tid; idx < nvec; idx += 256) {
        int r = idx >> 4, c = idx & 15;
        dzg[idx] = tile[r * LDW + c];
    }
}

extern "C" void kernel_launch(void* const* d_in, const int* in_sizes, int n_in,
                              void* d_out, int out_size, void* d_ws, size_t ws_size,
                              hipStream_t stream) {
    const float* t  = (const float*)d_in[0];
    const float* z  = (const float*)d_in[1];
    const float* W1 = (const float*)d_in[2];
    const float* b1 = (const float*)d_in[3];
    const float* W2 = (const float*)d_in[4];
    const float* b2 = (const float*)d_in[5];
    const float* W3 = (const float*)d_in[6];
    const float* b3 = (const float*)d_in[7];

    const int n = in_sizes[1] / IO_DIM;   // 500000
    float* ws   = (float*)d_ws;
    float* out  = (float*)d_out;
    float* dz   = out;
    float* dlog = out + (size_t)n * IO_DIM;

    cnf_prep<<<17, 128, 0, stream>>>(t, W1, b1, W2, b2, W3, b3, ws);

    const int grid = (n + TILE_ROWS - 1) / TILE_ROWS;
    cnf_main<<<grid, 256, 0, stream>>>(z, ws, dz, dlog, n);
}